// Round 2
// baseline (86.342 us; speedup 1.0000x reference)
//
#include <hip/hip_runtime.h>

// Problem constants (from reference): B=128, A=128, D=8, F=256, BF=16 (bonds unused)
#define NB 128
#define NA 128
#define ND 8
#define NF 256
#define NF4 (NF / 4)   // 64 float4 per feature row

// clang-native 4-float vector: accepted by __builtin_nontemporal_store
// (HIP's float4 is a HIP_vector_type class and is rejected).
typedef float nfloat4 __attribute__((ext_vector_type(4)));

// One wave (64 lanes) per atom: lane i owns float4 i of the 256-float row.
// Block = 256 threads = 4 atoms. Edge values are wave-uniform: we force them
// into SGPRs with readfirstlane so row selection / degree math runs on the
// scalar pipe and each gather is a single saddr-form global_load_dwordx4.
__global__ __launch_bounds__(256) void NeuralGraphPool_52072183497147_kernel(
        const float4* __restrict__ atoms,   // (B, A, F) as float4 rows
        const int*    __restrict__ edges,   // (B, A, D)
        float4*       __restrict__ out)     // (B, A, F)
{
    const int tid   = threadIdx.x;
    const int lane  = tid & 63;                       // float4 index in row
    const int aIdx  = (blockIdx.x << 2) + (tid >> 6); // global atom index b*A + a
    const int b     = aIdx >> 7;                      // / NA
    const int base  = aIdx * NF4;

    // self feature (also warms L2 for other atoms' gathers of this row)
    float4 v = atoms[base + lane];

    // edges: 8 ints = 32 B, wave-uniform address -> two broadcast int4 loads
    const int4* e4 = reinterpret_cast<const int4*>(edges + aIdx * ND);
    const int4 ea = e4[0];
    const int4 eb = e4[1];
    int er[ND] = {ea.x, ea.y, ea.z, ea.w, eb.x, eb.y, eb.z, eb.w};

    // batch slice base: all gathers stay within this 128 KB slice (L2-resident)
    const float4* __restrict__ bbase = atoms + (b << 7) * NF4;

    int deg = 0;
    #pragma unroll
    for (int d = 0; d < ND; ++d) {
        // value is uniform across the wave; readfirstlane moves it to an SGPR
        const int  ed = __builtin_amdgcn_readfirstlane(er[d]);
        const bool ok = (ed >= 0);
        deg += ok ? 1 : 0;                 // scalar-pipe bookkeeping
        // padding edge (-1): reference gathers the zero pad-row -> contributes
        // fmax(v, 0). Branch-free: load row 0 and scale by 0 -> identical result.
        const int   row = ok ? ed : 0;     // s_cselect
        const float m   = ok ? 1.0f : 0.0f;
        const float4 n  = bbase[row * NF4 + lane];  // saddr + lane*16 gather
        v.x = fmaxf(v.x, n.x * m);
        v.y = fmaxf(v.y, n.y * m);
        v.z = fmaxf(v.z, n.z * m);
        v.w = fmaxf(v.w, n.w * m);
    }

    if (deg == 0) {
        v.x = 0.0f; v.y = 0.0f; v.z = 0.0f; v.w = 0.0f;
    }
    // output is write-once, never re-read: keep it out of L2 so the gather
    // slices stay resident. Reinterpret through a native clang vector type.
    nfloat4 nv;
    nv.x = v.x; nv.y = v.y; nv.z = v.z; nv.w = v.w;
    __builtin_nontemporal_store(nv, reinterpret_cast<nfloat4*>(&out[base + lane]));
}

extern "C" void kernel_launch(void* const* d_in, const int* in_sizes, int n_in,
                              void* d_out, int out_size, void* d_ws, size_t ws_size,
                              hipStream_t stream) {
    const float4* atoms = (const float4*)d_in[0];
    // d_in[1] = bonds (B,A,D,BF) float32 — unused by the reference.
    const int*    edges = (const int*)d_in[2];
    float4*       out   = (float4*)d_out;

    const int nAtoms = NB * NA;            // 16384
    dim3 grid(nAtoms / 4);                 // 4096 blocks
    dim3 block(256);
    NeuralGraphPool_52072183497147_kernel<<<grid, block, 0, stream>>>(atoms, edges, out);
}